// Round 1
// baseline (380.122 us; speedup 1.0000x reference)
//
#include <hip/hip_runtime.h>
#include <hip/hip_bf16.h>

typedef short short8 __attribute__((ext_vector_type(8)));
typedef float f32x4 __attribute__((ext_vector_type(4)));

#define NB 8
#define NN 4096
#define NC 256
#define QT 64
#define KT 32

__device__ __forceinline__ unsigned short f2bf(float f) {
    unsigned int u = __float_as_uint(f);
    u += 0x7fffu + ((u >> 16) & 1u);
    return (unsigned short)(u >> 16);
}

// [B][C][N] f32  ->  [B][N][C] bf16, += pos[N][C], * scale
__global__ void tp_kernel(const float* __restrict__ src, const float* __restrict__ pos,
                          unsigned short* __restrict__ dst, float scale) {
    __shared__ float tile[64][65];
    const int n0 = blockIdx.x * 64;
    const int c0 = blockIdx.y * 64;
    const int b  = blockIdx.z;
    const int nl = threadIdx.x & 63;
    const int cq = threadIdx.x >> 6;
    #pragma unroll
    for (int i = 0; i < 16; ++i) {
        int cc = cq + i * 4;
        tile[cc][nl] = src[((size_t)(b * NC + c0 + cc)) * NN + n0 + nl];
    }
    __syncthreads();
    #pragma unroll
    for (int i = 0; i < 16; ++i) {
        int nn = cq + i * 4;
        float v = tile[nl][nn] + pos[(size_t)(n0 + nn) * NC + c0 + nl];
        dst[((size_t)(b * NN + n0 + nn)) * NC + c0 + nl] = f2bf(v * scale);
    }
}

// [B][C][N] f32 -> bf16 (same layout) : V^T slab
__global__ void castv_kernel(const float4* __restrict__ src, ushort4* __restrict__ dst, int n4) {
    int i = blockIdx.x * 256 + threadIdx.x;
    if (i >= n4) return;
    float4 v = src[i];
    ushort4 o;
    o.x = f2bf(v.x); o.y = f2bf(v.y); o.z = f2bf(v.z); o.w = f2bf(v.w);
    dst[i] = o;
}

#define K_OFF 0
#define V_OFF 16384
#define P_OFF (16384 + 20480)
#define SMEM_BYTES (P_OFF + 4 * 1280)

__global__ __launch_bounds__(256) void attn_kernel(const unsigned short* __restrict__ qb,
                                                   const unsigned short* __restrict__ kb,
                                                   const unsigned short* __restrict__ vt,
                                                   float* __restrict__ out) {
    __shared__ __align__(16) unsigned char smem[SMEM_BYTES];
    const int tid  = threadIdx.x;
    const int w    = tid >> 6;
    const int lane = tid & 63;
    const int g    = lane >> 4;
    const int r16  = lane & 15;
    const int qt   = blockIdx.x;
    const int b    = blockIdx.y;

    // Q fragments: wave owns 16 q-rows; A-layout row = lane%16, kd = kk*32 + g*8 + j
    short8 qf[8];
    const unsigned short* qrow = qb + ((size_t)(b * NN + qt * QT + w * 16 + r16)) * NC + g * 8;
    #pragma unroll
    for (int kk = 0; kk < 8; ++kk) qf[kk] = *(const short8*)(qrow + kk * 32);

    f32x4 acc[16];
    f32x4 zero4 = {0.f, 0.f, 0.f, 0.f};
    #pragma unroll
    for (int t = 0; t < 16; ++t) acc[t] = zero4;
    float mprev[4] = {-1e30f, -1e30f, -1e30f, -1e30f};
    float lsum[4]  = {0.f, 0.f, 0.f, 0.f};

    const char* ksrc_base     = (const char*)(kb + (size_t)b * NN * NC);
    const unsigned short* vtb = vt + (size_t)b * NC * NN;

    for (int kt = 0; kt < NN / KT; ++kt) {
        __syncthreads();
        // stage K tile [KT][NC] bf16 (rows 512B, XOR-swizzled), coalesced global reads
        {
            const char* ks = ksrc_base + (size_t)kt * KT * NC * 2;
            #pragma unroll
            for (int i = 0; i < 4; ++i) {
                int o = i * 4096 + tid * 16;
                int row = o >> 9, bp = o & 511;
                int4 d = *(const int4*)(ks + o);
                *(int4*)(smem + K_OFF + row * 512 + (bp ^ ((row & 7) << 4))) = d;
            }
            // stage V slab [NC][KT] bf16, rows padded 64B->80B (conflict-free 5-slot stride)
            const unsigned short* vs = vtb + kt * KT;
            #pragma unroll
            for (int i = 0; i < 4; ++i) {
                int c = i * 64 + (tid >> 2), part = tid & 3;
                int4 d = *(const int4*)((const char*)(vs + (size_t)c * NN) + part * 16);
                *(int4*)(smem + V_OFF + c * 80 + part * 16) = d;
            }
        }
        __syncthreads();

        // S = Q K^T : per wave 16 rows x 32 cols (2 col-subtiles)
        f32x4 s0 = zero4, s1 = zero4;
        const int sw = (r16 & 7) << 4;
        #pragma unroll
        for (int kk = 0; kk < 8; ++kk) {
            int bcol = kk * 64 + g * 16;
            short8 k0 = *(const short8*)(smem + K_OFF + r16 * 512 + (bcol ^ sw));
            short8 k1 = *(const short8*)(smem + K_OFF + (16 + r16) * 512 + (bcol ^ sw));
            s0 = __builtin_amdgcn_mfma_f32_16x16x32_bf16(qf[kk], k0, s0, 0, 0, 0);
            s1 = __builtin_amdgcn_mfma_f32_16x16x32_bf16(qf[kk], k1, s1, 0, 0, 0);
        }

        // online softmax in log2 domain (scale folded into Q); rows = g*4+r
        float al[4], p0[4], p1[4];
        #pragma unroll
        for (int r = 0; r < 4; ++r) {
            float mx = fmaxf(s0[r], s1[r]);
            mx = fmaxf(mx, __shfl_xor(mx, 1));
            mx = fmaxf(mx, __shfl_xor(mx, 2));
            mx = fmaxf(mx, __shfl_xor(mx, 4));
            mx = fmaxf(mx, __shfl_xor(mx, 8));
            float mnew = fmaxf(mprev[r], mx);
            al[r] = exp2f(mprev[r] - mnew);
            p0[r] = exp2f(s0[r] - mnew);
            p1[r] = exp2f(s1[r] - mnew);
            float ps = p0[r] + p1[r];
            ps += __shfl_xor(ps, 1);
            ps += __shfl_xor(ps, 2);
            ps += __shfl_xor(ps, 4);
            ps += __shfl_xor(ps, 8);
            lsum[r] = lsum[r] * al[r] + ps;
            mprev[r] = mnew;
        }
        f32x4 alv = {al[0], al[1], al[2], al[3]};
        #pragma unroll
        for (int t = 0; t < 16; ++t) acc[t] *= alv;

        // P -> per-wave LDS [16][KT] bf16, rows padded to 80B (C/D write, A-layout read)
        {
            unsigned char* pb = smem + P_OFF + w * 1280;
            #pragma unroll
            for (int r = 0; r < 4; ++r) {
                *(unsigned short*)(pb + (g * 4 + r) * 80 + r16 * 2)      = f2bf(p0[r]);
                *(unsigned short*)(pb + (g * 4 + r) * 80 + 32 + r16 * 2) = f2bf(p1[r]);
            }
        }
        // O += P V : A = P (16x32), B[kd][c] read from V^T slab (kd contiguous)
        short8 pa = *(const short8*)(smem + P_OFF + w * 1280 + r16 * 80 + g * 16);
        #pragma unroll
        for (int t = 0; t < 16; ++t) {
            short8 vf = *(const short8*)(smem + V_OFF + (t * 16 + r16) * 80 + g * 16);
            acc[t] = __builtin_amdgcn_mfma_f32_16x16x32_bf16(pa, vf, acc[t], 0, 0, 0);
        }
    }

    // epilogue: normalize, transpose O through LDS (two 128-channel halves), coalesced store
    f32x4 invv = {1.f / lsum[0], 1.f / lsum[1], 1.f / lsum[2], 1.f / lsum[3]};
    #pragma unroll
    for (int half = 0; half < 2; ++half) {
        __syncthreads();
        #pragma unroll
        for (int i = 0; i < 8; ++i) {
            int t = half * 8 + i;
            f32x4 v = acc[t] * invv;
            *(f32x4*)(smem + (i * 16 + r16) * 272 + (w * 16 + g * 4) * 4) = v;
        }
        __syncthreads();
        #pragma unroll
        for (int i = 0; i < 32; ++i) {
            int cl = i * 4 + w;
            float val = *(const float*)(smem + cl * 272 + lane * 4);
            out[((size_t)(b * NC + half * 128 + cl)) * NN + qt * QT + lane] = val;
        }
    }
}

extern "C" void kernel_launch(void* const* d_in, const int* in_sizes, int n_in,
                              void* d_out, int out_size, void* d_ws, size_t ws_size,
                              hipStream_t stream) {
    (void)in_sizes; (void)n_in; (void)out_size; (void)ws_size;
    const float* q    = (const float*)d_in[0];
    const float* k    = (const float*)d_in[1];
    const float* v    = (const float*)d_in[2];
    const float* qpos = (const float*)d_in[3];
    const float* kpos = (const float*)d_in[4];

    unsigned short* qb = (unsigned short*)d_ws;                  // 16.78 MB
    unsigned short* kb = qb + (size_t)NB * NN * NC;              // 16.78 MB
    unsigned short* vt = kb + (size_t)NB * NN * NC;              // 16.78 MB (needs ws >= 50.4 MB)

    const float qscale = 0.09016844005556021f; // log2(e) / sqrt(256)

    tp_kernel<<<dim3(64, 4, NB), 256, 0, stream>>>(q, qpos, qb, qscale);
    tp_kernel<<<dim3(64, 4, NB), 256, 0, stream>>>(k, kpos, kb, 1.0f);
    castv_kernel<<<dim3((NB * NC * NN / 4) / 256), 256, 0, stream>>>((const float4*)v, (ushort4*)vt, NB * NC * NN / 4);
    attn_kernel<<<dim3(NN / QT, NB), 256, 0, stream>>>(qb, kb, vt, (float*)d_out);
}

// Round 3
// 202.321 us; speedup vs baseline: 1.8788x; 1.8788x over previous
//
#include <hip/hip_runtime.h>
#include <hip/hip_bf16.h>

typedef short short8 __attribute__((ext_vector_type(8)));
typedef float f32x16 __attribute__((ext_vector_type(16)));
typedef unsigned int u32x4 __attribute__((ext_vector_type(4)));

#define NB 8
#define NN 4096
#define NC 256
#define KBLK 64
#define NT (NN / KBLK)

#define K_OFF 0
#define V_OFF 32768
#define ML_OFF 65536
#define SMEM_BYTES (ML_OFF + 1024)

typedef __attribute__((address_space(3))) unsigned char lds_uc;
typedef __attribute__((address_space(1))) const unsigned char glb_uc;

__device__ __forceinline__ void gload_lds16(const void* g, void* l) {
    __builtin_amdgcn_global_load_lds((const glb_uc*)g, (lds_uc*)l, 16, 0, 0);
}

__device__ __forceinline__ unsigned short f2bf(float f) {
    unsigned int u = __float_as_uint(f);
    u += 0x7fffu + ((u >> 16) & 1u);
    return (unsigned short)(u >> 16);
}

// [B][C][N] f32 -> [B][N][C] bf16, += pos[N][C], * scale
__global__ void tp_kernel(const float* __restrict__ src, const float* __restrict__ pos,
                          unsigned short* __restrict__ dst, float scale) {
    __shared__ float tile[64][65];
    const int n0 = blockIdx.x * 64;
    const int c0 = blockIdx.y * 64;
    const int b  = blockIdx.z;
    const int nl = threadIdx.x & 63;
    const int cq = threadIdx.x >> 6;
    #pragma unroll
    for (int i = 0; i < 16; ++i) {
        int cc = cq + i * 4;
        tile[cc][nl] = src[((size_t)(b * NC + c0 + cc)) * NN + n0 + nl];
    }
    __syncthreads();
    #pragma unroll
    for (int i = 0; i < 16; ++i) {
        int nn = cq + i * 4;
        float v = tile[nl][nn] + pos[(size_t)(n0 + nn) * NC + c0 + nl];
        dst[((size_t)(b * NN + n0 + nn)) * NC + c0 + nl] = f2bf(v * scale);
    }
}

// [B][C][N] f32 -> bf16 same layout (V^T slab)
__global__ void castv_kernel(const float4* __restrict__ src, ushort4* __restrict__ dst, int n4) {
    int i = blockIdx.x * 256 + threadIdx.x;
    if (i >= n4) return;
    float4 v = src[i];
    ushort4 o;
    o.x = f2bf(v.x); o.y = f2bf(v.y); o.z = f2bf(v.z); o.w = f2bf(v.w);
    dst[i] = o;
}

// Block: 4 waves = (qg in {0,1}) x (kh in {0,1}). Block owns 64 q-rows; wave (qg,kh)
// owns q-rows qg*32.. and the kh half of each staged 64-key tile (split-K w/ final merge).
// S = mfma(K, Q): C[key][q], q = lane&31.  O^T = mfma(Vt, P): C[dv][q], q = lane&31.
__global__ __launch_bounds__(256, 2) void attn_kernel(const unsigned short* __restrict__ qb,
                                                      const unsigned short* __restrict__ kb,
                                                      const unsigned short* __restrict__ vt,
                                                      float* __restrict__ out) {
    __shared__ __align__(16) unsigned char smem[SMEM_BYTES];
    const int tid  = threadIdx.x;
    const int w    = tid >> 6;
    const int lane = tid & 63;
    const int q5   = lane & 31;
    const int hi2  = lane >> 5;
    const int qg   = w >> 1;
    const int kh   = w & 1;
    const int qt   = blockIdx.x >> 3;   // b = blockIdx&7 -> batch pinned per XCD
    const int b    = blockIdx.x & 7;

    // Q fragments (B-operand): col q = q5, d = kk*16 + hi2*8 + j
    short8 qf[16];
    {
        const unsigned short* qr = qb + ((size_t)(b * NN + qt * 64 + qg * 32 + q5)) * NC + hi2 * 8;
        #pragma unroll
        for (int kk = 0; kk < 16; ++kk) qf[kk] = *(const short8*)(qr + kk * 16);
    }

    // staging source offsets (pre-swizzled global, linear LDS dest)
    const char* kbb = (const char*)(kb + (size_t)b * NN * NC);
    const char* vbb = (const char*)(vt + (size_t)b * NC * NN);
    unsigned kof[4];
    {
        unsigned x16 = (unsigned)(q5 * 16);
        #pragma unroll
        for (int j = 0; j < 4; ++j) {
            unsigned row = (unsigned)(w * 16 + j * 2 + hi2);
            kof[j] = row * 512 + (x16 ^ ((row & 7) << 4));
        }
    }
    unsigned vof;
    {
        unsigned r3 = (unsigned)(lane >> 3);
        vof = (unsigned)(w * 64 + r3) * 8192 + (((unsigned)((lane & 7) * 16)) ^ ((r3 & 7) << 4));
    }

    // LDS read addresses (kt-invariant)
    unsigned ka[4], va0, va1;
    {
        unsigned krow = (unsigned)(kh * 32 + q5);
        unsigned ksw  = (krow & 7) << 4;
        #pragma unroll
        for (int j = 0; j < 4; ++j)
            ka[j] = K_OFF + krow * 512 + (((unsigned)(j * 32 + hi2 * 16)) ^ ksw);
        unsigned vsw = ((unsigned)q5 & 7) << 4;
        va0 = V_OFF + (unsigned)q5 * 128 + (((unsigned)(kh * 64 + 0  + hi2 * 16)) ^ vsw);
        va1 = V_OFF + (unsigned)q5 * 128 + (((unsigned)(kh * 64 + 32 + hi2 * 16)) ^ vsw);
    }

    f32x16 acc[8];
    #pragma unroll
    for (int t = 0; t < 8; ++t)
        #pragma unroll
        for (int r = 0; r < 16; ++r) acc[t][r] = 0.f;
    float m = -1e30f, lsum = 0.f;

    for (int kt = 0; kt < NT; ++kt) {
        __syncthreads();   // previous tile fully consumed
        const char* kp = kbb + (size_t)kt * (KBLK * NC * 2);
        const char* vp = vbb + vof + (size_t)kt * (KBLK * 2);
        #pragma unroll
        for (int i = 0; i < 8; ++i) {
            gload_lds16(kp + kof[i & 3] + (i >> 2) * 4096, smem + K_OFF + (w * 8 + i) * 1024);
            gload_lds16(vp + i * 65536,                    smem + V_OFF + (w * 8 + i) * 1024);
        }
        __syncthreads();   // implicit vmcnt(0) drain before barrier -> tile ready

        // S = K·Q  -> C[key][q]
        f32x16 s;
        #pragma unroll
        for (int r = 0; r < 16; ++r) s[r] = 0.f;
        #pragma unroll
        for (int kk = 0; kk < 16; ++kk) {
            short8 kf = *(const short8*)(smem + ka[kk & 3] + (kk >> 2) * 128);
            s = __builtin_amdgcn_mfma_f32_32x32x16_bf16(kf, qf[kk], s, 0, 0, 0);
        }

        // per-lane online softmax (q = q5); keys split lane<->lane+32
        float pm = fmaxf(fmaxf(fmaxf(s[0], s[1]), fmaxf(s[2], s[3])),
                         fmaxf(fmaxf(s[4], s[5]), fmaxf(s[6], s[7])));
        pm = fmaxf(pm, fmaxf(fmaxf(fmaxf(s[8], s[9]), fmaxf(s[10], s[11])),
                             fmaxf(fmaxf(s[12], s[13]), fmaxf(s[14], s[15]))));
        pm = fmaxf(pm, __shfl_xor(pm, 32));
        if (__any(pm > m + 8.0f)) {    // defer-max (T13)
            float mn = fmaxf(m, pm);
            float al = exp2f(m - mn);
            lsum *= al;
            #pragma unroll
            for (int t = 0; t < 8; ++t) acc[t] *= al;
            m = mn;
        }
        float p[16];
        float ps = 0.f;
        #pragma unroll
        for (int i = 0; i < 16; ++i) { p[i] = exp2f(s[i] - m); ps += p[i]; }
        ps += __shfl_xor(ps, 32);
        lsum += ps;

        // P -> bf16 B-operand frags via cvt_pk + permlane32_swap (T12).
        // permlane32_swap semantics: vdst.row1 (lanes>=32) <-> vsrc.row0 (lanes<32).
        // Need: d0 = own c0 (row0) | partner c2 (row1)  => swap(c0, c2), vdst = c0.
        unsigned c0, c1, c2, c3, c4, c5, c6, c7;
        asm("v_cvt_pk_bf16_f32 %0, %1, %2" : "=v"(c0) : "v"(p[0]),  "v"(p[1]));
        asm("v_cvt_pk_bf16_f32 %0, %1, %2" : "=v"(c1) : "v"(p[2]),  "v"(p[3]));
        asm("v_cvt_pk_bf16_f32 %0, %1, %2" : "=v"(c2) : "v"(p[4]),  "v"(p[5]));
        asm("v_cvt_pk_bf16_f32 %0, %1, %2" : "=v"(c3) : "v"(p[6]),  "v"(p[7]));
        asm("v_cvt_pk_bf16_f32 %0, %1, %2" : "=v"(c4) : "v"(p[8]),  "v"(p[9]));
        asm("v_cvt_pk_bf16_f32 %0, %1, %2" : "=v"(c5) : "v"(p[10]), "v"(p[11]));
        asm("v_cvt_pk_bf16_f32 %0, %1, %2" : "=v"(c6) : "v"(p[12]), "v"(p[13]));
        asm("v_cvt_pk_bf16_f32 %0, %1, %2" : "=v"(c7) : "v"(p[14]), "v"(p[15]));
        asm("v_permlane32_swap_b32 %0, %1" : "+v"(c0), "+v"(c2));  // c0=d0, c2=d2 (ks0)
        asm("v_permlane32_swap_b32 %0, %1" : "+v"(c1), "+v"(c3));  // c1=d1, c3=d3
        asm("v_permlane32_swap_b32 %0, %1" : "+v"(c4), "+v"(c6));  // ks1
        asm("v_permlane32_swap_b32 %0, %1" : "+v"(c5), "+v"(c7));
        u32x4 w0 = {c0, c1, c2, c3};
        u32x4 w1 = {c4, c5, c6, c7};
        short8 pf0 = __builtin_bit_cast(short8, w0);
        short8 pf1 = __builtin_bit_cast(short8, w1);

        // O^T += Vt·P -> C[dv][q]
        #pragma unroll
        for (int t = 0; t < 8; ++t) {
            short8 vf0 = *(const short8*)(smem + va0 + t * 4096);
            acc[t] = __builtin_amdgcn_mfma_f32_32x32x16_bf16(vf0, pf0, acc[t], 0, 0, 0);
            short8 vf1 = *(const short8*)(smem + va1 + t * 4096);
            acc[t] = __builtin_amdgcn_mfma_f32_32x32x16_bf16(vf1, pf1, acc[t], 0, 0, 0);
        }
    }

    // ---- cross-kh merge (split-K combine), then store O^T directly to [B][C][N] ----
    __syncthreads();
    *(float*)(smem + ML_OFF + ((qg * 2 + kh) * 2 + 0) * 128 + q5 * 4) = m;
    *(float*)(smem + ML_OFF + ((qg * 2 + kh) * 2 + 1) * 128 + q5 * 4) = lsum;
    __syncthreads();
    float mo  = *(const float*)(smem + ML_OFF + ((qg * 2 + (kh ^ 1)) * 2 + 0) * 128 + q5 * 4);
    float lo2 = *(const float*)(smem + ML_OFF + ((qg * 2 + (kh ^ 1)) * 2 + 1) * 128 + q5 * 4);
    float M  = fmaxf(m, mo);
    float sc = exp2f(m - M);
    float L  = lsum * sc + lo2 * exp2f(mo - M);

    if (kh == 1) {  // partner dumps scaled partial O into (reused) K/V LDS space
        #pragma unroll
        for (int t = 0; t < 8; ++t)
            #pragma unroll
            for (int r = 0; r < 16; ++r) {
                int dvl = (r & 3) + 8 * (r >> 2) + hi2 * 4;
                *(float*)(smem + qg * 32768 + t * 4096 + dvl * 128 + q5 * 4) = acc[t][r] * sc;
            }
    }
    __syncthreads();
    if (kh == 0) {
        float invL = 1.0f / L;
        const size_t obase = (size_t)b * NC * NN + (size_t)(qt * 64 + qg * 32) + q5;
        #pragma unroll
        for (int t = 0; t < 8; ++t)
            #pragma unroll
            for (int r = 0; r < 16; ++r) {
                int dvl = (r & 3) + 8 * (r >> 2) + hi2 * 4;
                float po = *(const float*)(smem + qg * 32768 + t * 4096 + dvl * 128 + q5 * 4);
                float val = (acc[t][r] * sc + po) * invL;
                out[obase + (size_t)(t * 32 + dvl) * NN] = val;
            }
    }
}

extern "C" void kernel_launch(void* const* d_in, const int* in_sizes, int n_in,
                              void* d_out, int out_size, void* d_ws, size_t ws_size,
                              hipStream_t stream) {
    (void)in_sizes; (void)n_in; (void)out_size; (void)ws_size;
    const float* q    = (const float*)d_in[0];
    const float* k    = (const float*)d_in[1];
    const float* v    = (const float*)d_in[2];
    const float* qpos = (const float*)d_in[3];
    const float* kpos = (const float*)d_in[4];

    unsigned short* qb = (unsigned short*)d_ws;
    unsigned short* kb = qb + (size_t)NB * NN * NC;
    unsigned short* vt = kb + (size_t)NB * NN * NC;

    const float qscale = 0.09016844005556021f; // log2(e) / sqrt(256)

    tp_kernel<<<dim3(64, 4, NB), 256, 0, stream>>>(q, qpos, qb, qscale);
    tp_kernel<<<dim3(64, 4, NB), 256, 0, stream>>>(k, kpos, kb, 1.0f);
    castv_kernel<<<dim3((NB * NC * NN / 4) / 256), 256, 0, stream>>>((const float4*)v, (ushort4*)vt, NB * NC * NN / 4);
    attn_kernel<<<dim3(512), 256, 0, stream>>>(qb, kb, vt, (float*)d_out);
}